// Round 1
// baseline (119.006 us; speedup 1.0000x reference)
//
#include <hip/hip_runtime.h>

// GraphAttentionRela: B=16, ATT=64, RELA=128, RNN=1024, HID=512
// K1: att_obj[b,a,h] = obj_vecs_e[b,a,:] @ W_obj[:,h] + b_obj[h]
// K2: scores[b,a,r] = sum_h tanh(p_rela[b,r,h] + att_obj[b,a,h]) * w_alpha[h] + b_alpha
//     weight = renorm(softmax(scores) * mask)
// K3: out[b,a,d] = sum_r weight[b,a,r] * rela_feats[b,r,d]

constexpr int B_   = 16;
constexpr int ATT  = 64;
constexpr int RELA = 128;
constexpr int RNN  = 1024;
constexpr int HID  = 512;
constexpr float EPS_ = 1e-8f;

__device__ __forceinline__ float fast_tanh(float x) {
    // tanh(x) = 1 - 2/(exp(2x)+1); saturates correctly for |x| large
    float e = __expf(2.f * x);
    return 1.f - 2.f / (e + 1.f);
}

// ---------------- K1: fp32 tiled GEMM  C[1024][512] = A[1024][1024] @ W[1024][512] + bias
// grid (HID/64, M/64) = (8,16), block 256, 4x4 per thread, BK=16
__global__ __launch_bounds__(256) void k1_gemm(const float* __restrict__ A,
                                               const float* __restrict__ W,
                                               const float* __restrict__ bias,
                                               float* __restrict__ C) {
    __shared__ float As[16][64];  // [k][m]
    __shared__ float Bs[16][64];  // [k][n]
    const int tid = threadIdx.x;
    const int tx = tid & 15, ty = tid >> 4;
    const int row0 = blockIdx.y * 64, col0 = blockIdx.x * 64;
    const int lr = tid >> 2;          // A row within tile 0..63
    const int lk = (tid & 3) << 2;    // A k offset 0,4,8,12
    const int bk = tid >> 4;          // B k row 0..15
    const int bn = (tid & 15) << 2;   // B col offset 0..60
    float acc[4][4] = {};
    for (int k0 = 0; k0 < RNN; k0 += 16) {
        const float4 av = *reinterpret_cast<const float4*>(&A[(size_t)(row0 + lr) * RNN + k0 + lk]);
        const float4 bv = *reinterpret_cast<const float4*>(&W[(size_t)(k0 + bk) * HID + col0 + bn]);
        As[lk + 0][lr] = av.x;
        As[lk + 1][lr] = av.y;
        As[lk + 2][lr] = av.z;
        As[lk + 3][lr] = av.w;
        *reinterpret_cast<float4*>(&Bs[bk][bn]) = bv;
        __syncthreads();
        #pragma unroll
        for (int kk = 0; kk < 16; ++kk) {
            const float4 a4 = *reinterpret_cast<const float4*>(&As[kk][ty << 2]);
            const float4 b4 = *reinterpret_cast<const float4*>(&Bs[kk][tx << 2]);
            const float avr[4] = {a4.x, a4.y, a4.z, a4.w};
            const float bvr[4] = {b4.x, b4.y, b4.z, b4.w};
            #pragma unroll
            for (int i = 0; i < 4; ++i)
                #pragma unroll
                for (int j = 0; j < 4; ++j)
                    acc[i][j] = fmaf(avr[i], bvr[j], acc[i][j]);
        }
        __syncthreads();
    }
    #pragma unroll
    for (int i = 0; i < 4; ++i) {
        const int r = row0 + (ty << 2) + i;
        #pragma unroll
        for (int j = 0; j < 4; ++j) {
            const int c = col0 + (tx << 2) + j;
            C[(size_t)r * HID + c] = acc[i][j] + bias[c];
        }
    }
}

// ---------------- K2: fused scores + softmax + mask + renorm -> weight[b*ATT+a][RELA]
// grid 1024 (one block per (b,a)), block 256 (4 waves). Each wave handles 32 r's;
// per r each lane owns 8 h values, wave shuffle-reduce.
__global__ __launch_bounds__(256) void k2_scores(const float* __restrict__ att_obj,
                                                 const float* __restrict__ p_rela,
                                                 const float* __restrict__ w_alpha,
                                                 const float* __restrict__ b_alpha_p,
                                                 const int* __restrict__ masks,
                                                 float* __restrict__ weight) {
    const int ba = blockIdx.x;       // b*ATT + a
    const int b = ba >> 6;           // / ATT
    const int tid = threadIdx.x;
    const int lane = tid & 63;
    const int wave = tid >> 6;
    const int h0 = lane << 3;        // 8 h per lane

    float q[8], w[8];
    {
        const float4 t0 = *reinterpret_cast<const float4*>(&att_obj[(size_t)ba * HID + h0]);
        const float4 t1 = *reinterpret_cast<const float4*>(&att_obj[(size_t)ba * HID + h0 + 4]);
        q[0] = t0.x; q[1] = t0.y; q[2] = t0.z; q[3] = t0.w;
        q[4] = t1.x; q[5] = t1.y; q[6] = t1.z; q[7] = t1.w;
        const float4 u0 = *reinterpret_cast<const float4*>(&w_alpha[h0]);
        const float4 u1 = *reinterpret_cast<const float4*>(&w_alpha[h0 + 4]);
        w[0] = u0.x; w[1] = u0.y; w[2] = u0.z; w[3] = u0.w;
        w[4] = u1.x; w[5] = u1.y; w[6] = u1.z; w[7] = u1.w;
    }
    __shared__ float s_sc[RELA];
    const float b_alpha = b_alpha_p[0];

    for (int r = wave; r < RELA; r += 4) {
        const float* p = &p_rela[((size_t)b * RELA + r) * HID + h0];
        const float4 p0 = *reinterpret_cast<const float4*>(p);
        const float4 p1 = *reinterpret_cast<const float4*>(p + 4);
        const float pv[8] = {p0.x, p0.y, p0.z, p0.w, p1.x, p1.y, p1.z, p1.w};
        float s = 0.f;
        #pragma unroll
        for (int j = 0; j < 8; ++j)
            s = fmaf(fast_tanh(pv[j] + q[j]), w[j], s);
        #pragma unroll
        for (int off = 32; off > 0; off >>= 1)
            s += __shfl_down(s, off);
        if (lane == 0) s_sc[r] = s + b_alpha;
    }
    __syncthreads();

    if (wave == 0) {
        const float s0 = s_sc[lane], s1 = s_sc[lane + 64];
        float m = fmaxf(s0, s1);
        #pragma unroll
        for (int off = 32; off > 0; off >>= 1)
            m = fmaxf(m, __shfl_xor(m, off));
        const float e0 = __expf(s0 - m), e1 = __expf(s1 - m);
        float sum = e0 + e1;
        #pragma unroll
        for (int off = 32; off > 0; off >>= 1)
            sum += __shfl_xor(sum, off);
        const float inv = 1.f / sum;  // plain softmax denom (no mask), matches reference
        const float m0 = (float)masks[(size_t)ba * RELA + lane];
        const float m1 = (float)masks[(size_t)ba * RELA + lane + 64];
        const float w0 = e0 * inv * m0;
        const float w1 = e1 * inv * m1;
        float ms = w0 + w1;
        #pragma unroll
        for (int off = 32; off > 0; off >>= 1)
            ms += __shfl_xor(ms, off);
        const float inv2 = 1.f / (ms + EPS_);
        weight[(size_t)ba * RELA + lane]      = w0 * inv2;
        weight[(size_t)ba * RELA + lane + 64] = w1 * inv2;
    }
}

// ---------------- K3: out[b,a,d] = sum_r weight[b,a,r] * rela[b,r,d]
// grid (B, ATT/4), block 256; each thread owns 4 d (float4) covering all 1024 d, 4 a's per block
__global__ __launch_bounds__(256) void k3_wsum(const float* __restrict__ weight,
                                               const float* __restrict__ rela,
                                               float* __restrict__ out) {
    const int b = blockIdx.x;
    const int a0 = blockIdx.y << 2;
    const int tid = threadIdx.x;
    const int d0 = tid << 2;
    __shared__ float s_w[4][RELA];
    for (int i = tid; i < 4 * RELA; i += 256)
        s_w[i >> 7][i & 127] = weight[((size_t)b * ATT + a0 + (i >> 7)) * RELA + (i & 127)];
    __syncthreads();
    float4 acc[4] = {};
    for (int r = 0; r < RELA; ++r) {
        const float4 x = *reinterpret_cast<const float4*>(&rela[((size_t)b * RELA + r) * RNN + d0]);
        #pragma unroll
        for (int a = 0; a < 4; ++a) {
            const float wv = s_w[a][r];
            acc[a].x = fmaf(wv, x.x, acc[a].x);
            acc[a].y = fmaf(wv, x.y, acc[a].y);
            acc[a].z = fmaf(wv, x.z, acc[a].z);
            acc[a].w = fmaf(wv, x.w, acc[a].w);
        }
    }
    #pragma unroll
    for (int a = 0; a < 4; ++a)
        *reinterpret_cast<float4*>(&out[((size_t)b * ATT + a0 + a) * RNN + d0]) = acc[a];
}

extern "C" void kernel_launch(void* const* d_in, const int* in_sizes, int n_in,
                              void* d_out, int out_size, void* d_ws, size_t ws_size,
                              hipStream_t stream) {
    const float* obj_vecs = (const float*)d_in[0];  // [16,64,1024]
    const float* rela     = (const float*)d_in[1];  // [16,128,1024]
    const float* p_rela   = (const float*)d_in[2];  // [16,128,512]
    const float* W_obj    = (const float*)d_in[3];  // [1024,512]
    const float* b_obj    = (const float*)d_in[4];  // [512]
    const float* w_alpha  = (const float*)d_in[5];  // [512]
    const float* b_alpha  = (const float*)d_in[6];  // [1]
    const int*   masks    = (const int*)d_in[7];    // [16,64,128]
    float* out = (float*)d_out;                     // [16,64,1024]

    float* att_obj = (float*)d_ws;                          // 1024*512 f32 = 2 MB
    float* weight  = att_obj + (size_t)B_ * ATT * HID;      // 1024*128 f32 = 512 KB

    k1_gemm<<<dim3(HID / 64, (B_ * ATT) / 64), 256, 0, stream>>>(obj_vecs, W_obj, b_obj, att_obj);
    k2_scores<<<dim3(B_ * ATT), 256, 0, stream>>>(att_obj, p_rela, w_alpha, b_alpha, masks, weight);
    k3_wsum<<<dim3(B_, ATT / 4), 256, 0, stream>>>(weight, rela, out);
}

// Round 2
// 96.173 us; speedup vs baseline: 1.2374x; 1.2374x over previous
//
#include <hip/hip_runtime.h>

// GraphAttentionRela: B=16, ATT=64, RELA=128, RNN=1024, HID=512
// K1: split-K=4 fp32 GEMM -> partials P[4][1024][512]
// K2: q = sum_s P[s] + b_obj (split-K fixup fused); scores/softmax/mask/renorm
// K3: out[b,a,d] = sum_r weight[b,a,r] * rela[b,r,d]

constexpr int B_   = 16;
constexpr int ATT  = 64;
constexpr int RELA = 128;
constexpr int RNN  = 1024;
constexpr int HID  = 512;
constexpr int M_   = B_ * ATT;   // 1024
constexpr int KSPLIT = 4;
constexpr int KCH  = RNN / KSPLIT;  // 256
constexpr float EPS_ = 1e-8f;

__device__ __forceinline__ float fast_tanh(float x) {
    float e = __expf(2.f * x);
    return 1.f - 2.f / (e + 1.f);
}

// ---------------- K1: fp32 GEMM, 64x64 tile, BK=16, split-K=4, reg-prefetch dbuf
// grid (HID/64, M/64, KSPLIT) = (8,16,4) = 512 blocks, 256 thr
__global__ __launch_bounds__(256) void k1_gemm_splitk(const float* __restrict__ A,
                                                      const float* __restrict__ W,
                                                      float* __restrict__ P) {
    __shared__ float As[16][64];  // [k][m]
    __shared__ float Bs[16][64];  // [k][n]
    const int tid = threadIdx.x;
    const int tx = tid & 15, ty = tid >> 4;
    const int row0 = blockIdx.y * 64, col0 = blockIdx.x * 64;
    const int kbase = blockIdx.z * KCH;
    const int lr = tid >> 2;          // A row in tile 0..63
    const int lk = (tid & 3) << 2;    // A k offset 0,4,8,12
    const int bk = tid >> 4;          // B k row 0..15
    const int bn = (tid & 15) << 2;   // B col offset
    float acc[4][4] = {};
    const float* Aptr = &A[(size_t)(row0 + lr) * RNN + kbase + lk];
    const float* Wptr = &W[(size_t)(kbase + bk) * HID + col0 + bn];
    float4 av = *reinterpret_cast<const float4*>(Aptr);
    float4 bv = *reinterpret_cast<const float4*>(Wptr);
    for (int k0 = 0; k0 < KCH; k0 += 16) {
        As[lk + 0][lr] = av.x;
        As[lk + 1][lr] = av.y;
        As[lk + 2][lr] = av.z;
        As[lk + 3][lr] = av.w;
        *reinterpret_cast<float4*>(&Bs[bk][bn]) = bv;
        __syncthreads();
        if (k0 + 16 < KCH) {  // prefetch next k-slab into regs (overlaps compute)
            av = *reinterpret_cast<const float4*>(Aptr + k0 + 16);
            bv = *reinterpret_cast<const float4*>(Wptr + (size_t)(k0 + 16) * HID);
        }
        #pragma unroll
        for (int kk = 0; kk < 16; ++kk) {
            const float4 a4 = *reinterpret_cast<const float4*>(&As[kk][ty << 2]);
            const float4 b4 = *reinterpret_cast<const float4*>(&Bs[kk][tx << 2]);
            const float avr[4] = {a4.x, a4.y, a4.z, a4.w};
            const float bvr[4] = {b4.x, b4.y, b4.z, b4.w};
            #pragma unroll
            for (int i = 0; i < 4; ++i)
                #pragma unroll
                for (int j = 0; j < 4; ++j)
                    acc[i][j] = fmaf(avr[i], bvr[j], acc[i][j]);
        }
        __syncthreads();
    }
    float* dst = &P[(size_t)blockIdx.z * M_ * HID];
    #pragma unroll
    for (int i = 0; i < 4; ++i) {
        const int r = row0 + (ty << 2) + i;
        const int c = col0 + (tx << 2);
        float4 o;
        o.x = acc[i][0]; o.y = acc[i][1]; o.z = acc[i][2]; o.w = acc[i][3];
        *reinterpret_cast<float4*>(&dst[(size_t)r * HID + c]) = o;
    }
}

// ---------------- K2: fused split-K reduce + bias + scores + softmax + mask + renorm
// grid 1024 (one block per (b,a)), block 256 (4 waves)
__global__ __launch_bounds__(256) void k2_scores(const float* __restrict__ P,
                                                 const float* __restrict__ b_obj,
                                                 const float* __restrict__ p_rela,
                                                 const float* __restrict__ w_alpha,
                                                 const float* __restrict__ b_alpha_p,
                                                 const int* __restrict__ masks,
                                                 float* __restrict__ weight) {
    const int ba = blockIdx.x;       // b*ATT + a
    const int b = ba >> 6;
    const int tid = threadIdx.x;
    const int lane = tid & 63;
    const int wave = tid >> 6;
    const int h0 = lane << 3;        // 8 h per lane

    float q[8], w[8];
    {
        const float4 t0 = *reinterpret_cast<const float4*>(&b_obj[h0]);
        const float4 t1 = *reinterpret_cast<const float4*>(&b_obj[h0 + 4]);
        q[0] = t0.x; q[1] = t0.y; q[2] = t0.z; q[3] = t0.w;
        q[4] = t1.x; q[5] = t1.y; q[6] = t1.z; q[7] = t1.w;
        #pragma unroll
        for (int s = 0; s < KSPLIT; ++s) {
            const float* pp = &P[(size_t)s * M_ * HID + (size_t)ba * HID + h0];
            const float4 p0 = *reinterpret_cast<const float4*>(pp);
            const float4 p1 = *reinterpret_cast<const float4*>(pp + 4);
            q[0] += p0.x; q[1] += p0.y; q[2] += p0.z; q[3] += p0.w;
            q[4] += p1.x; q[5] += p1.y; q[6] += p1.z; q[7] += p1.w;
        }
        const float4 u0 = *reinterpret_cast<const float4*>(&w_alpha[h0]);
        const float4 u1 = *reinterpret_cast<const float4*>(&w_alpha[h0 + 4]);
        w[0] = u0.x; w[1] = u0.y; w[2] = u0.z; w[3] = u0.w;
        w[4] = u1.x; w[5] = u1.y; w[6] = u1.z; w[7] = u1.w;
    }
    __shared__ float s_sc[RELA];
    const float b_alpha = b_alpha_p[0];

    // each wave: 16 iterations of 2 adjacent r's (ILP: two reduce chains interleave)
    for (int r = wave * 2; r < RELA; r += 8) {
        const float* pa = &p_rela[((size_t)b * RELA + r) * HID + h0];
        const float* pb = pa + HID;
        const float4 a0 = *reinterpret_cast<const float4*>(pa);
        const float4 a1 = *reinterpret_cast<const float4*>(pa + 4);
        const float4 c0 = *reinterpret_cast<const float4*>(pb);
        const float4 c1 = *reinterpret_cast<const float4*>(pb + 4);
        const float avv[8] = {a0.x, a0.y, a0.z, a0.w, a1.x, a1.y, a1.z, a1.w};
        const float bvv[8] = {c0.x, c0.y, c0.z, c0.w, c1.x, c1.y, c1.z, c1.w};
        float sa = 0.f, sb = 0.f;
        #pragma unroll
        for (int j = 0; j < 8; ++j) {
            sa = fmaf(fast_tanh(avv[j] + q[j]), w[j], sa);
            sb = fmaf(fast_tanh(bvv[j] + q[j]), w[j], sb);
        }
        #pragma unroll
        for (int off = 32; off > 0; off >>= 1) {
            sa += __shfl_down(sa, off);
            sb += __shfl_down(sb, off);
        }
        if (lane == 0) {
            s_sc[r]     = sa + b_alpha;
            s_sc[r + 1] = sb + b_alpha;
        }
    }
    __syncthreads();

    if (wave == 0) {
        const float s0 = s_sc[lane], s1 = s_sc[lane + 64];
        float m = fmaxf(s0, s1);
        #pragma unroll
        for (int off = 32; off > 0; off >>= 1)
            m = fmaxf(m, __shfl_xor(m, off));
        const float e0 = __expf(s0 - m), e1 = __expf(s1 - m);
        float sum = e0 + e1;
        #pragma unroll
        for (int off = 32; off > 0; off >>= 1)
            sum += __shfl_xor(sum, off);
        const float inv = 1.f / sum;
        const float m0 = (float)masks[(size_t)ba * RELA + lane];
        const float m1 = (float)masks[(size_t)ba * RELA + lane + 64];
        const float w0 = e0 * inv * m0;
        const float w1 = e1 * inv * m1;
        float ms = w0 + w1;
        #pragma unroll
        for (int off = 32; off > 0; off >>= 1)
            ms += __shfl_xor(ms, off);
        const float inv2 = 1.f / (ms + EPS_);
        weight[(size_t)ba * RELA + lane]      = w0 * inv2;
        weight[(size_t)ba * RELA + lane + 64] = w1 * inv2;
    }
}

// ---------------- K3: out[b,a,d] = sum_r weight[b,a,r] * rela[b,r,d]
// grid (B, ATT/8), block 256; 8 a's per block, thread owns one float4 of d
__global__ __launch_bounds__(256) void k3_wsum(const float* __restrict__ weight,
                                               const float* __restrict__ rela,
                                               float* __restrict__ out) {
    const int b = blockIdx.x;
    const int a0 = blockIdx.y << 3;
    const int tid = threadIdx.x;
    const int d0 = tid << 2;
    __shared__ float s_w[8][RELA];
    for (int i = tid; i < 8 * RELA; i += 256)
        s_w[i >> 7][i & 127] = weight[((size_t)b * ATT + a0 + (i >> 7)) * RELA + (i & 127)];
    __syncthreads();
    float4 acc[8] = {};
    for (int r = 0; r < RELA; ++r) {
        const float4 x = *reinterpret_cast<const float4*>(&rela[((size_t)b * RELA + r) * RNN + d0]);
        #pragma unroll
        for (int a = 0; a < 8; ++a) {
            const float wv = s_w[a][r];
            acc[a].x = fmaf(wv, x.x, acc[a].x);
            acc[a].y = fmaf(wv, x.y, acc[a].y);
            acc[a].z = fmaf(wv, x.z, acc[a].z);
            acc[a].w = fmaf(wv, x.w, acc[a].w);
        }
    }
    #pragma unroll
    for (int a = 0; a < 8; ++a)
        *reinterpret_cast<float4*>(&out[((size_t)b * ATT + a0 + a) * RNN + d0]) = acc[a];
}

extern "C" void kernel_launch(void* const* d_in, const int* in_sizes, int n_in,
                              void* d_out, int out_size, void* d_ws, size_t ws_size,
                              hipStream_t stream) {
    const float* obj_vecs = (const float*)d_in[0];  // [16,64,1024]
    const float* rela     = (const float*)d_in[1];  // [16,128,1024]
    const float* p_rela   = (const float*)d_in[2];  // [16,128,512]
    const float* W_obj    = (const float*)d_in[3];  // [1024,512]
    const float* b_obj    = (const float*)d_in[4];  // [512]
    const float* w_alpha  = (const float*)d_in[5];  // [512]
    const float* b_alpha  = (const float*)d_in[6];  // [1]
    const int*   masks    = (const int*)d_in[7];    // [16,64,128]
    float* out = (float*)d_out;                     // [16,64,1024]

    float* P      = (float*)d_ws;                              // 4*1024*512 f32 = 8 MB
    float* weight = P + (size_t)KSPLIT * M_ * HID;             // 1024*128 f32 = 512 KB

    k1_gemm_splitk<<<dim3(HID / 64, M_ / 64, KSPLIT), 256, 0, stream>>>(obj_vecs, W_obj, P);
    k2_scores<<<dim3(M_), 256, 0, stream>>>(P, b_obj, p_rela, w_alpha, b_alpha, masks, weight);
    k3_wsum<<<dim3(B_, ATT / 8), 256, 0, stream>>>(weight, rela, out);
}

// Round 3
// 94.886 us; speedup vs baseline: 1.2542x; 1.0136x over previous
//
#include <hip/hip_runtime.h>

// GraphAttentionRela: B=16, ATT=64, RELA=128, RNN=1024, HID=512
// K1 : split-K=4 fp32 GEMM -> partials P[4][1024][512]   (As padded, no bank conflicts)
// K2a: scores[ba][r] = sum_h tanh(p_rela+q)*w_alpha + b_alpha   (4 a's per block: 4x p reuse)
// K2b: softmax+mask+renorm -> weightT[b][r][a]  (transposed, aliases P)
// K3 : out[b] = weightT[b]^T @ rela[b], d-split, LDS-staged, rela read exactly once

constexpr int B_   = 16;
constexpr int ATT  = 64;
constexpr int RELA = 128;
constexpr int RNN  = 1024;
constexpr int HID  = 512;
constexpr int M_   = B_ * ATT;      // 1024
constexpr int KSPLIT = 4;
constexpr int KCH  = RNN / KSPLIT;  // 256
constexpr float EPS_ = 1e-8f;

__device__ __forceinline__ float fast_tanh(float x) {
    float e = __expf(2.f * x);
    return 1.f - 2.f / (e + 1.f);
}

// ---------------- K1: fp32 GEMM, 64x64 tile, BK=16, split-K=4, reg-prefetch dbuf
// grid (8,16,4) = 512 blocks, 256 thr
__global__ __launch_bounds__(256) void k1_gemm_splitk(const float* __restrict__ A,
                                                      const float* __restrict__ W,
                                                      float* __restrict__ P) {
    __shared__ float As[16][68];  // [k][m], +4 pad: write banks 2-way only
    __shared__ float Bs[16][64];  // [k][n]
    const int tid = threadIdx.x;
    const int tx = tid & 15, ty = tid >> 4;
    const int row0 = blockIdx.y * 64, col0 = blockIdx.x * 64;
    const int kbase = blockIdx.z * KCH;
    const int lr = tid >> 2;
    const int lk = (tid & 3) << 2;
    const int bk = tid >> 4;
    const int bn = (tid & 15) << 2;
    float acc[4][4] = {};
    const float* Aptr = &A[(size_t)(row0 + lr) * RNN + kbase + lk];
    const float* Wptr = &W[(size_t)(kbase + bk) * HID + col0 + bn];
    float4 av = *reinterpret_cast<const float4*>(Aptr);
    float4 bv = *reinterpret_cast<const float4*>(Wptr);
    for (int k0 = 0; k0 < KCH; k0 += 16) {
        As[lk + 0][lr] = av.x;
        As[lk + 1][lr] = av.y;
        As[lk + 2][lr] = av.z;
        As[lk + 3][lr] = av.w;
        *reinterpret_cast<float4*>(&Bs[bk][bn]) = bv;
        __syncthreads();
        if (k0 + 16 < KCH) {
            av = *reinterpret_cast<const float4*>(Aptr + k0 + 16);
            bv = *reinterpret_cast<const float4*>(Wptr + (size_t)(k0 + 16) * HID);
        }
        #pragma unroll
        for (int kk = 0; kk < 16; ++kk) {
            const float4 a4 = *reinterpret_cast<const float4*>(&As[kk][ty << 2]);
            const float4 b4 = *reinterpret_cast<const float4*>(&Bs[kk][tx << 2]);
            const float avr[4] = {a4.x, a4.y, a4.z, a4.w};
            const float bvr[4] = {b4.x, b4.y, b4.z, b4.w};
            #pragma unroll
            for (int i = 0; i < 4; ++i)
                #pragma unroll
                for (int j = 0; j < 4; ++j)
                    acc[i][j] = fmaf(avr[i], bvr[j], acc[i][j]);
        }
        __syncthreads();
    }
    float* dst = &P[(size_t)blockIdx.z * M_ * HID];
    #pragma unroll
    for (int i = 0; i < 4; ++i) {
        const int r = row0 + (ty << 2) + i;
        const int c = col0 + (tx << 2);
        float4 o;
        o.x = acc[i][0]; o.y = acc[i][1]; o.z = acc[i][2]; o.w = acc[i][3];
        *reinterpret_cast<float4*>(&dst[(size_t)r * HID + c]) = o;
    }
}

// ---------------- K2a: scores for 4 a's x 64 r's per block
// grid (B, ATT/4, RELA/64) = (16,16,2) = 512 blocks, 256 thr (4 waves)
__global__ __launch_bounds__(256) void k2a_scores(const float* __restrict__ P,
                                                  const float* __restrict__ b_obj,
                                                  const float* __restrict__ p_rela,
                                                  const float* __restrict__ w_alpha,
                                                  const float* __restrict__ b_alpha_p,
                                                  float* __restrict__ scores) {
    const int b  = blockIdx.x;
    const int a0 = blockIdx.y << 2;
    const int r0 = blockIdx.z << 6;
    const int tid = threadIdx.x;
    const int lane = tid & 63;
    const int wave = tid >> 6;
    const int h0 = lane << 3;

    float q[4][8], w[8];
    #pragma unroll
    for (int a = 0; a < 4; ++a) {
        const int ba = (b << 6) + a0 + a;
        float4 t0 = *reinterpret_cast<const float4*>(&b_obj[h0]);
        float4 t1 = *reinterpret_cast<const float4*>(&b_obj[h0 + 4]);
        q[a][0] = t0.x; q[a][1] = t0.y; q[a][2] = t0.z; q[a][3] = t0.w;
        q[a][4] = t1.x; q[a][5] = t1.y; q[a][6] = t1.z; q[a][7] = t1.w;
        #pragma unroll
        for (int s = 0; s < KSPLIT; ++s) {
            const float* pp = &P[(size_t)s * M_ * HID + (size_t)ba * HID + h0];
            const float4 p0 = *reinterpret_cast<const float4*>(pp);
            const float4 p1 = *reinterpret_cast<const float4*>(pp + 4);
            q[a][0] += p0.x; q[a][1] += p0.y; q[a][2] += p0.z; q[a][3] += p0.w;
            q[a][4] += p1.x; q[a][5] += p1.y; q[a][6] += p1.z; q[a][7] += p1.w;
        }
    }
    {
        const float4 u0 = *reinterpret_cast<const float4*>(&w_alpha[h0]);
        const float4 u1 = *reinterpret_cast<const float4*>(&w_alpha[h0 + 4]);
        w[0] = u0.x; w[1] = u0.y; w[2] = u0.z; w[3] = u0.w;
        w[4] = u1.x; w[5] = u1.y; w[6] = u1.z; w[7] = u1.w;
    }
    const float b_alpha = b_alpha_p[0];

    // wave handles 16 r's, 2 per iter; register-prefetch the next pair of p rows
    int r = r0 + (wave << 1);
    const float* pr = &p_rela[((size_t)b * RELA + r) * HID + h0];
    float4 A0 = *reinterpret_cast<const float4*>(pr);
    float4 A1 = *reinterpret_cast<const float4*>(pr + 4);
    float4 C0 = *reinterpret_cast<const float4*>(pr + HID);
    float4 C1 = *reinterpret_cast<const float4*>(pr + HID + 4);
    #pragma unroll
    for (int it = 0; it < 8; ++it, r += 8) {
        float4 nA0, nA1, nC0, nC1;
        if (it < 7) {
            const float* pn = &p_rela[((size_t)b * RELA + r + 8) * HID + h0];
            nA0 = *reinterpret_cast<const float4*>(pn);
            nA1 = *reinterpret_cast<const float4*>(pn + 4);
            nC0 = *reinterpret_cast<const float4*>(pn + HID);
            nC1 = *reinterpret_cast<const float4*>(pn + HID + 4);
        }
        const float pv0[8] = {A0.x, A0.y, A0.z, A0.w, A1.x, A1.y, A1.z, A1.w};
        const float pv1[8] = {C0.x, C0.y, C0.z, C0.w, C1.x, C1.y, C1.z, C1.w};
        float s[4][2] = {};
        #pragma unroll
        for (int j = 0; j < 8; ++j) {
            #pragma unroll
            for (int a = 0; a < 4; ++a) {
                s[a][0] = fmaf(fast_tanh(pv0[j] + q[a][j]), w[j], s[a][0]);
                s[a][1] = fmaf(fast_tanh(pv1[j] + q[a][j]), w[j], s[a][1]);
            }
        }
        #pragma unroll
        for (int off = 32; off > 0; off >>= 1)
            #pragma unroll
            for (int a = 0; a < 4; ++a) {
                s[a][0] += __shfl_down(s[a][0], off);
                s[a][1] += __shfl_down(s[a][1], off);
            }
        if (lane == 0) {
            #pragma unroll
            for (int a = 0; a < 4; ++a) {
                const int ba = (b << 6) + a0 + a;
                scores[(size_t)ba * RELA + r]     = s[a][0] + b_alpha;
                scores[(size_t)ba * RELA + r + 1] = s[a][1] + b_alpha;
            }
        }
        A0 = nA0; A1 = nA1; C0 = nC0; C1 = nC1;
    }
}

// ---------------- K2b: softmax + mask + renorm -> weightT[b][r][a]
// grid 256, block 256 (4 waves); wave w handles ba = blockIdx*4 + w
__global__ __launch_bounds__(256) void k2b_softmax(const float* __restrict__ scores,
                                                   const int* __restrict__ masks,
                                                   float* __restrict__ weightT) {
    const int tid = threadIdx.x;
    const int lane = tid & 63;
    const int wave = tid >> 6;
    const int ba = (blockIdx.x << 2) + wave;
    const int b = ba >> 6, a = ba & 63;

    const float s0 = scores[(size_t)ba * RELA + lane];
    const float s1 = scores[(size_t)ba * RELA + lane + 64];
    float m = fmaxf(s0, s1);
    #pragma unroll
    for (int off = 32; off > 0; off >>= 1)
        m = fmaxf(m, __shfl_xor(m, off));
    const float e0 = __expf(s0 - m), e1 = __expf(s1 - m);
    float sum = e0 + e1;
    #pragma unroll
    for (int off = 32; off > 0; off >>= 1)
        sum += __shfl_xor(sum, off);
    const float inv = 1.f / sum;
    const float m0 = (float)masks[(size_t)ba * RELA + lane];
    const float m1 = (float)masks[(size_t)ba * RELA + lane + 64];
    const float w0 = e0 * inv * m0;
    const float w1 = e1 * inv * m1;
    float ms = w0 + w1;
    #pragma unroll
    for (int off = 32; off > 0; off >>= 1)
        ms += __shfl_xor(ms, off);
    const float inv2 = 1.f / (ms + EPS_);
    float* wb = &weightT[(size_t)b * RELA * ATT];
    wb[(size_t)lane * ATT + a]        = w0 * inv2;
    wb[(size_t)(lane + 64) * ATT + a] = w1 * inv2;
}

// ---------------- K3: out[b] = weightT[b]^T @ rela[b]; grid (B, RNN/64)=(16,16), 256 thr
// LDS: weightT[b] (32 KB) + rela chunk [32][64] (8 KB). rela read exactly once chip-wide.
__global__ __launch_bounds__(256) void k3_wsum(const float* __restrict__ weightT,
                                               const float* __restrict__ rela,
                                               float* __restrict__ out) {
    const int b = blockIdx.x;
    const int d_base = blockIdx.y << 6;
    const int tid = threadIdx.x;
    const int col = tid & 15;   // float4 column within 64-d tile
    const int a0 = (tid >> 4) << 2;  // 4 a's per thread

    __shared__ float wT_s[RELA * ATT];  // [r][a] 32 KB
    __shared__ float rs[32 * 64];       // [rr][d] 8 KB
    #pragma unroll
    for (int i = 0; i < 8; ++i) {
        const int fi = tid + (i << 8);  // float4 index into 8192 floats
        *reinterpret_cast<float4*>(&wT_s[fi << 2]) =
            *reinterpret_cast<const float4*>(&weightT[((size_t)b * RELA * ATT) + ((size_t)fi << 2)]);
    }
    float4 acc[4] = {};
    for (int rc = 0; rc < 4; ++rc) {
        __syncthreads();
        #pragma unroll
        for (int i = 0; i < 2; ++i) {
            const int fi = tid + (i << 8);        // 512 float4 = 32r x 64d
            const int rr = fi >> 4, c = fi & 15;
            *reinterpret_cast<float4*>(&rs[(rr << 6) + (c << 2)]) =
                *reinterpret_cast<const float4*>(&rela[((size_t)b * RELA + (rc << 5) + rr) * RNN + d_base + (c << 2)]);
        }
        __syncthreads();
        #pragma unroll 8
        for (int rr = 0; rr < 32; ++rr) {
            const float4 x = *reinterpret_cast<const float4*>(&rs[(rr << 6) + (col << 2)]);
            const float4 wv = *reinterpret_cast<const float4*>(&wT_s[(((rc << 5) + rr) << 6) + a0]);
            const float wr[4] = {wv.x, wv.y, wv.z, wv.w};
            #pragma unroll
            for (int ai = 0; ai < 4; ++ai) {
                acc[ai].x = fmaf(wr[ai], x.x, acc[ai].x);
                acc[ai].y = fmaf(wr[ai], x.y, acc[ai].y);
                acc[ai].z = fmaf(wr[ai], x.z, acc[ai].z);
                acc[ai].w = fmaf(wr[ai], x.w, acc[ai].w);
            }
        }
    }
    #pragma unroll
    for (int ai = 0; ai < 4; ++ai)
        *reinterpret_cast<float4*>(&out[((size_t)(b << 6) + a0 + ai) * RNN + d_base + (col << 2)]) = acc[ai];
}

extern "C" void kernel_launch(void* const* d_in, const int* in_sizes, int n_in,
                              void* d_out, int out_size, void* d_ws, size_t ws_size,
                              hipStream_t stream) {
    const float* obj_vecs = (const float*)d_in[0];
    const float* rela     = (const float*)d_in[1];
    const float* p_rela   = (const float*)d_in[2];
    const float* W_obj    = (const float*)d_in[3];
    const float* b_obj    = (const float*)d_in[4];
    const float* w_alpha  = (const float*)d_in[5];
    const float* b_alpha  = (const float*)d_in[6];
    const int*   masks    = (const int*)d_in[7];
    float* out = (float*)d_out;

    float* P       = (float*)d_ws;                       // 4*1024*512 f32 = 8 MB
    float* scores  = P + (size_t)KSPLIT * M_ * HID;      // 1024*128 f32 = 512 KB
    float* weightT = P;  // aliases P: K2b runs after K2a's last read of P (same stream)

    k1_gemm_splitk<<<dim3(HID / 64, M_ / 64, KSPLIT), 256, 0, stream>>>(obj_vecs, W_obj, P);
    k2a_scores<<<dim3(B_, ATT / 4, RELA / 64), 256, 0, stream>>>(P, b_obj, p_rela, w_alpha, b_alpha, scores);
    k2b_softmax<<<dim3(M_ / 4), 256, 0, stream>>>(scores, masks, weightT);
    k3_wsum<<<dim3(B_, RNN / 64), 256, 0, stream>>>(weightT, rela, out);
}

// Round 4
// 72.103 us; speedup vs baseline: 1.6505x; 1.3160x over previous
//
#include <hip/hip_runtime.h>

// GraphAttentionRela: B=16, ATT=64, RELA=128, RNN=1024, HID=512
// K1 : split-K=4 fp32 GEMM -> P[4][1024][512]
// K1b: att_obj = sum_s P[s] + b_obj
// K2a: lane=a structure, ZERO cross-lane reduces: partials[ba][hg][r] over 8 h-groups
// K2b: sum partials + b_alpha, softmax+mask+renorm -> weight[b][a][r] (coalesced)
// K3 : out[b] = weight^T @ rela[b]; weight transposed during LDS staging

constexpr int B_   = 16;
constexpr int ATT  = 64;
constexpr int RELA = 128;
constexpr int RNN  = 1024;
constexpr int HID  = 512;
constexpr int M_   = B_ * ATT;      // 1024
constexpr int KSPLIT = 4;
constexpr int KCH  = RNN / KSPLIT;  // 256
constexpr float EPS_ = 1e-8f;
// K2a tiling
constexpr int RT  = 16;             // r per block
constexpr int NRT = RELA / RT;      // 8
constexpr int HG  = 64;             // h per block
constexpr int NHG = HID / HG;       // 8
constexpr int HW  = 16;             // h per wave

__device__ __forceinline__ float fast_tanh(float x) {
    float e = __expf(2.f * x);
    return 1.f - 2.f / (e + 1.f);
}

// ---------------- K1: fp32 GEMM, 64x64 tile, BK=16, split-K=4, reg-prefetch dbuf
__global__ __launch_bounds__(256) void k1_gemm_splitk(const float* __restrict__ A,
                                                      const float* __restrict__ W,
                                                      float* __restrict__ P) {
    __shared__ float As[16][68];
    __shared__ float Bs[16][64];
    const int tid = threadIdx.x;
    const int tx = tid & 15, ty = tid >> 4;
    const int row0 = blockIdx.y * 64, col0 = blockIdx.x * 64;
    const int kbase = blockIdx.z * KCH;
    const int lr = tid >> 2;
    const int lk = (tid & 3) << 2;
    const int bk = tid >> 4;
    const int bn = (tid & 15) << 2;
    float acc[4][4] = {};
    const float* Aptr = &A[(size_t)(row0 + lr) * RNN + kbase + lk];
    const float* Wptr = &W[(size_t)(kbase + bk) * HID + col0 + bn];
    float4 av = *reinterpret_cast<const float4*>(Aptr);
    float4 bv = *reinterpret_cast<const float4*>(Wptr);
    for (int k0 = 0; k0 < KCH; k0 += 16) {
        As[lk + 0][lr] = av.x;
        As[lk + 1][lr] = av.y;
        As[lk + 2][lr] = av.z;
        As[lk + 3][lr] = av.w;
        *reinterpret_cast<float4*>(&Bs[bk][bn]) = bv;
        __syncthreads();
        if (k0 + 16 < KCH) {
            av = *reinterpret_cast<const float4*>(Aptr + k0 + 16);
            bv = *reinterpret_cast<const float4*>(Wptr + (size_t)(k0 + 16) * HID);
        }
        #pragma unroll
        for (int kk = 0; kk < 16; ++kk) {
            const float4 a4 = *reinterpret_cast<const float4*>(&As[kk][ty << 2]);
            const float4 b4 = *reinterpret_cast<const float4*>(&Bs[kk][tx << 2]);
            const float avr[4] = {a4.x, a4.y, a4.z, a4.w};
            const float bvr[4] = {b4.x, b4.y, b4.z, b4.w};
            #pragma unroll
            for (int i = 0; i < 4; ++i)
                #pragma unroll
                for (int j = 0; j < 4; ++j)
                    acc[i][j] = fmaf(avr[i], bvr[j], acc[i][j]);
        }
        __syncthreads();
    }
    float* dst = &P[(size_t)blockIdx.z * M_ * HID];
    #pragma unroll
    for (int i = 0; i < 4; ++i) {
        const int r = row0 + (ty << 2) + i;
        const int c = col0 + (tx << 2);
        float4 o;
        o.x = acc[i][0]; o.y = acc[i][1]; o.z = acc[i][2]; o.w = acc[i][3];
        *reinterpret_cast<float4*>(&dst[(size_t)r * HID + c]) = o;
    }
}

// ---------------- K1b: att_obj = sum_s P[s] + b_obj   (grid 512, 256 thr, float4/thr)
__global__ __launch_bounds__(256) void k1b_fixup(const float* __restrict__ P,
                                                 const float* __restrict__ b_obj,
                                                 float* __restrict__ att_obj) {
    const size_t fi = (size_t)blockIdx.x * 256 + threadIdx.x;   // float4 index
    const size_t off = fi << 2;
    const int c = (int)(off & (HID - 1));
    float4 s = *reinterpret_cast<const float4*>(&b_obj[c]);
    #pragma unroll
    for (int sp = 0; sp < KSPLIT; ++sp) {
        const float4 p = *reinterpret_cast<const float4*>(&P[(size_t)sp * M_ * HID + off]);
        s.x += p.x; s.y += p.y; s.z += p.z; s.w += p.w;
    }
    *reinterpret_cast<float4*>(&att_obj[off]) = s;
}

// ---------------- K2a: lane=a, acc[r] in registers, no cross-lane ops
// grid (B, NRT, NHG) = (16,8,8) = 1024 blocks, 256 thr (4 waves = 4 h-chunks of 16)
__global__ __launch_bounds__(256) void k2a_scores(const float* __restrict__ att_obj,
                                                  const float* __restrict__ p_rela,
                                                  const float* __restrict__ w_alpha,
                                                  float* __restrict__ partials) {
    const int b  = blockIdx.x;
    const int rt = blockIdx.y;
    const int hg = blockIdx.z;
    const int tid = threadIdx.x;
    const int lane = tid & 63;      // = a
    const int wave = tid >> 6;

    __shared__ float ps[RT][HG];        // 4 KB p tile (broadcast reads)
    __shared__ float red[4][ATT][RT];   // 16 KB wave partials

    {   // stage p tile: 16 rows x 64 floats, coalesced
        const int row = tid >> 4, c4 = (tid & 15) << 2;
        *reinterpret_cast<float4*>(&ps[row][c4]) =
            *reinterpret_cast<const float4*>(&p_rela[((size_t)b * RELA + rt * RT + row) * HID + hg * HG + c4]);
    }
    const int hbase = hg * HG + wave * HW;
    float4 q[4], wa[4];
    #pragma unroll
    for (int i = 0; i < 4; ++i) {
        q[i]  = *reinterpret_cast<const float4*>(&att_obj[(size_t)((b << 6) + lane) * HID + hbase + (i << 2)]);
        wa[i] = *reinterpret_cast<const float4*>(&w_alpha[hbase + (i << 2)]);
    }
    __syncthreads();

    float acc[RT] = {};
    #pragma unroll
    for (int i = 0; i < 4; ++i) {
        const float qq[4] = {q[i].x, q[i].y, q[i].z, q[i].w};
        const float ww[4] = {wa[i].x, wa[i].y, wa[i].z, wa[i].w};
        #pragma unroll
        for (int r = 0; r < RT; ++r) {
            const float4 p4 = *reinterpret_cast<const float4*>(&ps[r][wave * HW + (i << 2)]);
            const float pp[4] = {p4.x, p4.y, p4.z, p4.w};
            #pragma unroll
            for (int j = 0; j < 4; ++j)
                acc[r] = fmaf(fast_tanh(pp[j] + qq[j]), ww[j], acc[r]);
        }
    }

    // intra-block reduce over the 4 waves (h-chunks)
    #pragma unroll
    for (int r = 0; r < RT; r += 4) {
        float4 o; o.x = acc[r]; o.y = acc[r + 1]; o.z = acc[r + 2]; o.w = acc[r + 3];
        *reinterpret_cast<float4*>(&red[wave][lane][r]) = o;
    }
    __syncthreads();
    // 256 threads x 4 (a,r) values
    const int idx = tid << 2;           // a = idx>>4, r = idx&15 (r aligned to 4)
    const int a = idx >> 4, r = idx & 15;
    const float4 s0 = *reinterpret_cast<const float4*>(&red[0][a][r]);
    const float4 s1 = *reinterpret_cast<const float4*>(&red[1][a][r]);
    const float4 s2 = *reinterpret_cast<const float4*>(&red[2][a][r]);
    const float4 s3 = *reinterpret_cast<const float4*>(&red[3][a][r]);
    float4 o;
    o.x = s0.x + s1.x + s2.x + s3.x;
    o.y = s0.y + s1.y + s2.y + s3.y;
    o.z = s0.z + s1.z + s2.z + s3.z;
    o.w = s0.w + s1.w + s2.w + s3.w;
    const size_t ba = (size_t)(b << 6) + a;
    *reinterpret_cast<float4*>(&partials[(ba * NHG + hg) * RELA + rt * RT + r]) = o;
}

// ---------------- K2b: sum 8 h-partials + b_alpha, softmax+mask+renorm -> weight[b][a][r]
// grid 256, block 256 (wave = one ba)
__global__ __launch_bounds__(256) void k2b_softmax(const float* __restrict__ partials,
                                                   const float* __restrict__ b_alpha_p,
                                                   const int* __restrict__ masks,
                                                   float* __restrict__ weight) {
    const int tid = threadIdx.x;
    const int lane = tid & 63;
    const int wave = tid >> 6;
    const int ba = (blockIdx.x << 2) + wave;

    const float* pp = &partials[(size_t)ba * NHG * RELA];
    float s0 = 0.f, s1 = 0.f;
    #pragma unroll
    for (int hs = 0; hs < NHG; ++hs) {
        s0 += pp[hs * RELA + lane];
        s1 += pp[hs * RELA + lane + 64];
    }
    const float b_alpha = b_alpha_p[0];
    s0 += b_alpha; s1 += b_alpha;

    float m = fmaxf(s0, s1);
    #pragma unroll
    for (int off = 32; off > 0; off >>= 1)
        m = fmaxf(m, __shfl_xor(m, off));
    const float e0 = __expf(s0 - m), e1 = __expf(s1 - m);
    float sum = e0 + e1;
    #pragma unroll
    for (int off = 32; off > 0; off >>= 1)
        sum += __shfl_xor(sum, off);
    const float inv = 1.f / sum;
    const float m0 = (float)masks[(size_t)ba * RELA + lane];
    const float m1 = (float)masks[(size_t)ba * RELA + lane + 64];
    const float w0 = e0 * inv * m0;
    const float w1 = e1 * inv * m1;
    float ms = w0 + w1;
    #pragma unroll
    for (int off = 32; off > 0; off >>= 1)
        ms += __shfl_xor(ms, off);
    const float inv2 = 1.f / (ms + EPS_);
    weight[(size_t)ba * RELA + lane]      = w0 * inv2;
    weight[(size_t)ba * RELA + lane + 64] = w1 * inv2;
}

// ---------------- K3: out[b] = weight[b]^T-ish @ rela[b]; grid (B, RNN/64), 256 thr
__global__ __launch_bounds__(256) void k3_wsum(const float* __restrict__ weight,
                                               const float* __restrict__ rela,
                                               float* __restrict__ out) {
    const int b = blockIdx.x;
    const int d_base = blockIdx.y << 6;
    const int tid = threadIdx.x;
    const int col = tid & 15;        // float4 column in 64-d tile
    const int a0 = (tid >> 4) << 2;  // 4 a's per thread

    __shared__ float ws_s[ATT][132];   // [a][r], padded: b128 stores stay aligned
    __shared__ float rs[32 * 64];      // [rr][d] 8 KB
    #pragma unroll
    for (int i = 0; i < 8; ++i) {
        const int fi = tid + (i << 8);           // float4 index, 2048 total
        const int a = fi >> 5, r0 = (fi << 2) & 127;
        *reinterpret_cast<float4*>(&ws_s[a][r0]) =
            *reinterpret_cast<const float4*>(&weight[((size_t)b * ATT + a) * RELA + r0]);
    }
    float4 acc[4] = {};
    for (int rc = 0; rc < 4; ++rc) {
        __syncthreads();
        #pragma unroll
        for (int i = 0; i < 2; ++i) {
            const int fi = tid + (i << 8);
            const int rr = fi >> 4, c = fi & 15;
            *reinterpret_cast<float4*>(&rs[(rr << 6) + (c << 2)]) =
                *reinterpret_cast<const float4*>(&rela[((size_t)b * RELA + (rc << 5) + rr) * RNN + d_base + (c << 2)]);
        }
        __syncthreads();
        #pragma unroll 8
        for (int rr = 0; rr < 32; ++rr) {
            const float4 x = *reinterpret_cast<const float4*>(&rs[(rr << 6) + (col << 2)]);
            const int r = (rc << 5) + rr;
            #pragma unroll
            for (int ai = 0; ai < 4; ++ai) {
                const float wv = ws_s[a0 + ai][r];   // wave-uniform per 16-lane group: broadcast
                acc[ai].x = fmaf(wv, x.x, acc[ai].x);
                acc[ai].y = fmaf(wv, x.y, acc[ai].y);
                acc[ai].z = fmaf(wv, x.z, acc[ai].z);
                acc[ai].w = fmaf(wv, x.w, acc[ai].w);
            }
        }
    }
    #pragma unroll
    for (int ai = 0; ai < 4; ++ai)
        *reinterpret_cast<float4*>(&out[((size_t)(b << 6) + a0 + ai) * RNN + d_base + (col << 2)]) = acc[ai];
}

extern "C" void kernel_launch(void* const* d_in, const int* in_sizes, int n_in,
                              void* d_out, int out_size, void* d_ws, size_t ws_size,
                              hipStream_t stream) {
    const float* obj_vecs = (const float*)d_in[0];
    const float* rela     = (const float*)d_in[1];
    const float* p_rela   = (const float*)d_in[2];
    const float* W_obj    = (const float*)d_in[3];
    const float* b_obj    = (const float*)d_in[4];
    const float* w_alpha  = (const float*)d_in[5];
    const float* b_alpha  = (const float*)d_in[6];
    const int*   masks    = (const int*)d_in[7];
    float* out = (float*)d_out;

    float* att_obj  = (float*)d_ws;                         // [0, 2MB)
    float* P        = att_obj + (size_t)M_ * HID;           // [2MB, 10MB)
    float* partials = P;                                    // aliases P [2MB,6MB): P dead after k1b
    float* weight   = P + (size_t)M_ * NHG * RELA;          // [6MB, 6.5MB): also over dead P

    k1_gemm_splitk<<<dim3(HID / 64, M_ / 64, KSPLIT), 256, 0, stream>>>(obj_vecs, W_obj, P);
    k1b_fixup<<<dim3((M_ * HID / 4) / 256), 256, 0, stream>>>(P, b_obj, att_obj);
    k2a_scores<<<dim3(B_, NRT, NHG), 256, 0, stream>>>(att_obj, p_rela, w_alpha, partials);
    k2b_softmax<<<dim3(M_ / 4), 256, 0, stream>>>(partials, b_alpha, masks, weight);
    k3_wsum<<<dim3(B_, RNN / 64), 256, 0, stream>>>(weight, rela, out);
}

// Round 5
// 62.440 us; speedup vs baseline: 1.9059x; 1.1547x over previous
//
#include <hip/hip_runtime.h>

// GraphAttentionRela: B=16, ATT=64, RELA=128, RNN=1024, HID=512
// K1 : split-K=4 fp32 GEMM -> P[4][1024][512]
// K1b: att_obj = sum_s P[s] + b_obj
// K2a: lane=a, zero cross-lane reduces, conflict-free LDS, RT=8, grid 2048
// K2b: sum 8 h-partials + b_alpha, softmax+mask+renorm -> weight[b][a][r]
// K3 : out[b] = weight^T @ rela[b]

constexpr int B_   = 16;
constexpr int ATT  = 64;
constexpr int RELA = 128;
constexpr int RNN  = 1024;
constexpr int HID  = 512;
constexpr int M_   = B_ * ATT;      // 1024
constexpr int KSPLIT = 4;
constexpr int KCH  = RNN / KSPLIT;  // 256
constexpr float EPS_ = 1e-8f;
// K2a tiling
constexpr int RT  = 8;              // r per block
constexpr int NRT = RELA / RT;      // 16
constexpr int HG  = 64;             // h per block
constexpr int NHG = HID / HG;       // 8
constexpr int HW  = 16;             // h per wave

__device__ __forceinline__ float fast_tanh(float x) {
    // tanh(x) = 1 - 2/(exp2(x*2/ln2)+1); v_exp + v_rcp, no div sequence
    const float e = exp2f(x * 2.885390081777927f);
    return fmaf(-2.f, __builtin_amdgcn_rcpf(e + 1.f), 1.f);
}

// ---------------- K1: fp32 GEMM, 64x64 tile, BK=16, split-K=4, reg-prefetch dbuf
__global__ __launch_bounds__(256) void k1_gemm_splitk(const float* __restrict__ A,
                                                      const float* __restrict__ W,
                                                      float* __restrict__ P) {
    __shared__ float As[16][68];
    __shared__ float Bs[16][64];
    const int tid = threadIdx.x;
    const int tx = tid & 15, ty = tid >> 4;
    const int row0 = blockIdx.y * 64, col0 = blockIdx.x * 64;
    const int kbase = blockIdx.z * KCH;
    const int lr = tid >> 2;
    const int lk = (tid & 3) << 2;
    const int bk = tid >> 4;
    const int bn = (tid & 15) << 2;
    float acc[4][4] = {};
    const float* Aptr = &A[(size_t)(row0 + lr) * RNN + kbase + lk];
    const float* Wptr = &W[(size_t)(kbase + bk) * HID + col0 + bn];
    float4 av = *reinterpret_cast<const float4*>(Aptr);
    float4 bv = *reinterpret_cast<const float4*>(Wptr);
    for (int k0 = 0; k0 < KCH; k0 += 16) {
        As[lk + 0][lr] = av.x;
        As[lk + 1][lr] = av.y;
        As[lk + 2][lr] = av.z;
        As[lk + 3][lr] = av.w;
        *reinterpret_cast<float4*>(&Bs[bk][bn]) = bv;
        __syncthreads();
        if (k0 + 16 < KCH) {
            av = *reinterpret_cast<const float4*>(Aptr + k0 + 16);
            bv = *reinterpret_cast<const float4*>(Wptr + (size_t)(k0 + 16) * HID);
        }
        #pragma unroll
        for (int kk = 0; kk < 16; ++kk) {
            const float4 a4 = *reinterpret_cast<const float4*>(&As[kk][ty << 2]);
            const float4 b4 = *reinterpret_cast<const float4*>(&Bs[kk][tx << 2]);
            const float avr[4] = {a4.x, a4.y, a4.z, a4.w};
            const float bvr[4] = {b4.x, b4.y, b4.z, b4.w};
            #pragma unroll
            for (int i = 0; i < 4; ++i)
                #pragma unroll
                for (int j = 0; j < 4; ++j)
                    acc[i][j] = fmaf(avr[i], bvr[j], acc[i][j]);
        }
        __syncthreads();
    }
    float* dst = &P[(size_t)blockIdx.z * M_ * HID];
    #pragma unroll
    for (int i = 0; i < 4; ++i) {
        const int r = row0 + (ty << 2) + i;
        const int c = col0 + (tx << 2);
        float4 o;
        o.x = acc[i][0]; o.y = acc[i][1]; o.z = acc[i][2]; o.w = acc[i][3];
        *reinterpret_cast<float4*>(&dst[(size_t)r * HID + c]) = o;
    }
}

// ---------------- K1b: att_obj = sum_s P[s] + b_obj
__global__ __launch_bounds__(256) void k1b_fixup(const float* __restrict__ P,
                                                 const float* __restrict__ b_obj,
                                                 float* __restrict__ att_obj) {
    const size_t fi = (size_t)blockIdx.x * 256 + threadIdx.x;
    const size_t off = fi << 2;
    const int c = (int)(off & (HID - 1));
    float4 s = *reinterpret_cast<const float4*>(&b_obj[c]);
    #pragma unroll
    for (int sp = 0; sp < KSPLIT; ++sp) {
        const float4 p = *reinterpret_cast<const float4*>(&P[(size_t)sp * M_ * HID + off]);
        s.x += p.x; s.y += p.y; s.z += p.z; s.w += p.w;
    }
    *reinterpret_cast<float4*>(&att_obj[off]) = s;
}

// ---------------- K2a: lane=a, acc[RT] in regs, conflict-free LDS
// grid (B, NRT, NHG) = (16,16,8) = 2048 blocks, 256 thr (4 waves = 4 h-chunks of 16)
__global__ __launch_bounds__(256) void k2a_scores(const float* __restrict__ att_obj,
                                                  const float* __restrict__ p_rela,
                                                  const float* __restrict__ w_alpha,
                                                  float* __restrict__ partials) {
    const int b  = blockIdx.x;
    const int rt = blockIdx.y;
    const int hg = blockIdx.z;
    const int tid = threadIdx.x;
    const int lane = tid & 63;      // = a
    const int wave = tid >> 6;

    __shared__ float ps[RT][HG];        // 2 KB
    __shared__ float red[4][RT][ATT];   // 8 KB, [wave][r][a]: lane-contiguous

    if (tid < 128) {   // stage p tile: 8 rows x 16 float4, coalesced
        const int row = tid >> 4, c4 = (tid & 15) << 2;
        *reinterpret_cast<float4*>(&ps[row][c4]) =
            *reinterpret_cast<const float4*>(&p_rela[((size_t)b * RELA + rt * RT + row) * HID + hg * HG + c4]);
    }
    const int hbase = hg * HG + wave * HW;
    float4 q[4], wa[4];
    #pragma unroll
    for (int i = 0; i < 4; ++i) {
        q[i]  = *reinterpret_cast<const float4*>(&att_obj[(size_t)((b << 6) + lane) * HID + hbase + (i << 2)]);
        wa[i] = *reinterpret_cast<const float4*>(&w_alpha[hbase + (i << 2)]);
    }
    __syncthreads();

    float acc[RT] = {};
    #pragma unroll
    for (int i = 0; i < 4; ++i) {
        const float qq[4] = {q[i].x, q[i].y, q[i].z, q[i].w};
        const float ww[4] = {wa[i].x, wa[i].y, wa[i].z, wa[i].w};
        #pragma unroll
        for (int r = 0; r < RT; ++r) {
            const float4 p4 = *reinterpret_cast<const float4*>(&ps[r][wave * HW + (i << 2)]);  // wave-uniform: broadcast
            const float pp[4] = {p4.x, p4.y, p4.z, p4.w};
            #pragma unroll
            for (int j = 0; j < 4; ++j)
                acc[r] = fmaf(fast_tanh(pp[j] + qq[j]), ww[j], acc[r]);
        }
    }

    // conflict-free transposed write: lane-contiguous scalar stores
    #pragma unroll
    for (int r = 0; r < RT; ++r)
        red[wave][r][lane] = acc[r];
    __syncthreads();

    // reduce over 4 waves: thread (a = tid&63, rg = tid>>6) handles 2 r's
    const int a = tid & 63, rg = tid >> 6;
    float2 o;
    o.x = red[0][rg * 2][a] + red[1][rg * 2][a] + red[2][rg * 2][a] + red[3][rg * 2][a];
    o.y = red[0][rg * 2 + 1][a] + red[1][rg * 2 + 1][a] + red[2][rg * 2 + 1][a] + red[3][rg * 2 + 1][a];
    const size_t ba = (size_t)(b << 6) + a;
    *reinterpret_cast<float2*>(&partials[(ba * NHG + hg) * RELA + rt * RT + rg * 2]) = o;
}

// ---------------- K2b: sum 8 h-partials + b_alpha, softmax+mask+renorm -> weight[b][a][r]
__global__ __launch_bounds__(256) void k2b_softmax(const float* __restrict__ partials,
                                                   const float* __restrict__ b_alpha_p,
                                                   const int* __restrict__ masks,
                                                   float* __restrict__ weight) {
    const int tid = threadIdx.x;
    const int lane = tid & 63;
    const int wave = tid >> 6;
    const int ba = (blockIdx.x << 2) + wave;

    const float* pp = &partials[(size_t)ba * NHG * RELA];
    float s0 = 0.f, s1 = 0.f;
    #pragma unroll
    for (int hs = 0; hs < NHG; ++hs) {
        s0 += pp[hs * RELA + lane];
        s1 += pp[hs * RELA + lane + 64];
    }
    const float b_alpha = b_alpha_p[0];
    s0 += b_alpha; s1 += b_alpha;

    float m = fmaxf(s0, s1);
    #pragma unroll
    for (int off = 32; off > 0; off >>= 1)
        m = fmaxf(m, __shfl_xor(m, off));
    const float e0 = __expf(s0 - m), e1 = __expf(s1 - m);
    float sum = e0 + e1;
    #pragma unroll
    for (int off = 32; off > 0; off >>= 1)
        sum += __shfl_xor(sum, off);
    const float inv = 1.f / sum;
    const float m0 = (float)masks[(size_t)ba * RELA + lane];
    const float m1 = (float)masks[(size_t)ba * RELA + lane + 64];
    const float w0 = e0 * inv * m0;
    const float w1 = e1 * inv * m1;
    float ms = w0 + w1;
    #pragma unroll
    for (int off = 32; off > 0; off >>= 1)
        ms += __shfl_xor(ms, off);
    const float inv2 = 1.f / (ms + EPS_);
    weight[(size_t)ba * RELA + lane]      = w0 * inv2;
    weight[(size_t)ba * RELA + lane + 64] = w1 * inv2;
}

// ---------------- K3: out[b] = weight[b]^T @ rela[b]; grid (B, RNN/64), 256 thr
__global__ __launch_bounds__(256) void k3_wsum(const float* __restrict__ weight,
                                               const float* __restrict__ rela,
                                               float* __restrict__ out) {
    const int b = blockIdx.x;
    const int d_base = blockIdx.y << 6;
    const int tid = threadIdx.x;
    const int col = tid & 15;
    const int a0 = (tid >> 4) << 2;

    __shared__ float ws_s[ATT][132];
    __shared__ float rs[32 * 64];
    #pragma unroll
    for (int i = 0; i < 8; ++i) {
        const int fi = tid + (i << 8);
        const int a = fi >> 5, r0 = (fi << 2) & 127;
        *reinterpret_cast<float4*>(&ws_s[a][r0]) =
            *reinterpret_cast<const float4*>(&weight[((size_t)b * ATT + a) * RELA + r0]);
    }
    float4 acc[4] = {};
    for (int rc = 0; rc < 4; ++rc) {
        __syncthreads();
        #pragma unroll
        for (int i = 0; i < 2; ++i) {
            const int fi = tid + (i << 8);
            const int rr = fi >> 4, c = fi & 15;
            *reinterpret_cast<float4*>(&rs[(rr << 6) + (c << 2)]) =
                *reinterpret_cast<const float4*>(&rela[((size_t)b * RELA + (rc << 5) + rr) * RNN + d_base + (c << 2)]);
        }
        __syncthreads();
        #pragma unroll 8
        for (int rr = 0; rr < 32; ++rr) {
            const float4 x = *reinterpret_cast<const float4*>(&rs[(rr << 6) + (col << 2)]);
            const int r = (rc << 5) + rr;
            #pragma unroll
            for (int ai = 0; ai < 4; ++ai) {
                const float wv = ws_s[a0 + ai][r];
                acc[ai].x = fmaf(wv, x.x, acc[ai].x);
                acc[ai].y = fmaf(wv, x.y, acc[ai].y);
                acc[ai].z = fmaf(wv, x.z, acc[ai].z);
                acc[ai].w = fmaf(wv, x.w, acc[ai].w);
            }
        }
    }
    #pragma unroll
    for (int ai = 0; ai < 4; ++ai)
        *reinterpret_cast<float4*>(&out[((size_t)(b << 6) + a0 + ai) * RNN + d_base + (col << 2)]) = acc[ai];
}

extern "C" void kernel_launch(void* const* d_in, const int* in_sizes, int n_in,
                              void* d_out, int out_size, void* d_ws, size_t ws_size,
                              hipStream_t stream) {
    const float* obj_vecs = (const float*)d_in[0];
    const float* rela     = (const float*)d_in[1];
    const float* p_rela   = (const float*)d_in[2];
    const float* W_obj    = (const float*)d_in[3];
    const float* b_obj    = (const float*)d_in[4];
    const float* w_alpha  = (const float*)d_in[5];
    const float* b_alpha  = (const float*)d_in[6];
    const int*   masks    = (const int*)d_in[7];
    float* out = (float*)d_out;

    float* att_obj  = (float*)d_ws;                         // [0, 2MB)
    float* P        = att_obj + (size_t)M_ * HID;           // [2MB, 10MB)
    float* partials = P;                                    // aliases P (dead after k1b), 4MB
    float* weight   = P + (size_t)M_ * NHG * RELA;          // [6MB, 6.5MB)

    k1_gemm_splitk<<<dim3(HID / 64, M_ / 64, KSPLIT), 256, 0, stream>>>(obj_vecs, W_obj, P);
    k1b_fixup<<<dim3((M_ * HID / 4) / 256), 256, 0, stream>>>(P, b_obj, att_obj);
    k2a_scores<<<dim3(B_, NRT, NHG), 256, 0, stream>>>(att_obj, p_rela, w_alpha, partials);
    k2b_softmax<<<dim3(M_ / 4), 256, 0, stream>>>(partials, b_alpha, masks, weight);
    k3_wsum<<<dim3(B_, RNN / 64), 256, 0, stream>>>(weight, rela, out);
}